// Round 2
// baseline (412.098 us; speedup 1.0000x reference)
//
#include <hip/hip_runtime.h>

// Problem constants: B=64, T=4096, F=64, H=256, LAM=0.5, LAG=1, ALPHA=0.5, EPS=1e-8
constexpr int B = 64;
constexpr int T = 4096;
constexpr int F = 64;       // == wavefront size; lane <-> feature
constexpr int H = 256;
constexpr float EPSC = 1e-8f;
constexpr float ALPHAC = 0.5f;

constexpr int C = 128;              // scan chunk length (one wave-task per chunk)
constexpr int W = 48;               // warmup steps (lambda=0.5 -> 2^-48 state error)
constexpr int CHUNKS = T / C;       // 32 chunks per batch row
constexpr int NTASK = B * CHUNKS;   // 2048 wave-tasks
constexpr int SCAN_BLOCKS = NTASK / 4; // 512 blocks x 4 waves
constexpr int TILE = 32;            // LDS transpose tile (t-steps buffered per reduce)

constexpr int DOT_BLOCKS = 2048;    // full-occupancy streaming kernel

// ws layout (floats):
//   [0, B*T)                      wsum[b,t] = sum_f (1-|ac|)   (1 MB)
//   [B*T, B*T+DOT_BLOCKS)         penalty partials (per k_dot block)
//   [B*T+DOT_BLOCKS, +SCAN_BLOCKS) mse partials (per k_scan block)
#define WS_IRR 0
#define WS_PEN (B * T)
#define WS_MSE (B * T + DOT_BLOCKS)

// ---------------------------------------------------------------------------
// Kernel 1: chunked EWA scan over seq only (80 MB). Per wave-task (b,chunk):
// 128 steps; per step compute w = 1-|ac| and buffer it in an LDS tile
// [TILE][64] (stride 65 -> conflict-free). Every 32 steps, transpose-reduce:
// lane (l&31) sums half a row, shfl_xor(32) combines -> coalesced 128B write
// of wsum[b,t]. Replaces the 6-deep dependent butterfly per step.
// MSE folded in as a grid-stride tail.
// ---------------------------------------------------------------------------
__global__ __launch_bounds__(256) void k_scan(
    const float* __restrict__ seq,
    const float* __restrict__ inp,
    const float* __restrict__ tgt,
    float* __restrict__ ws) {
  __shared__ float lt[4][TILE][65];   // 33.3 KB; bank = (row + col) % 32
  const int lane = threadIdx.x & 63;
  const int wv = threadIdx.x >> 6;
  const int task = blockIdx.x * 4 + wv;
  const int b = task / CHUNKS;
  const int ci = task % CHUNKS;
  const int t0 = ci * C;

  const float* sp = seq + (size_t)b * T * F + lane;   // + t*F

  float m = 0.f, v = 0.f, c = 0.f;
  float xl = 0.f;

  if (ci == 0) {
    v = EPSC;  // exact initial state; t=0 handled in-loop (w=1 contribution)
  } else {
    // warmup: 48 seq-only steps, pipelined depth 4 (fully unrolled, const trip)
    const int ts = t0 - W;
    xl = sp[(ts - 1) * F];
    float xw[4];
#pragma unroll
    for (int j = 0; j < 4; ++j) xw[j] = sp[(ts + j) * F];
#pragma unroll
    for (int i = 0; i < W; ++i) {
      const float xt = xw[i & 3];
      if (i + 4 < W) xw[i & 3] = sp[(ts + i + 4) * F];
      m = 0.5f * (m + xt);
      const float d = xt - m;
      v = 0.5f * fmaf(d, d, v);
      c = 0.5f * fmaf(d, xl - m, c);
      xl = xt;
    }
  }

  // main loop: C steps in C/TILE tiles, register prefetch depth 8
  float xb[8];
#pragma unroll
  for (int j = 0; j < 8; ++j) xb[j] = sp[(t0 + j) * F];

  const int tr = lane & 31;
  const int half = lane >> 5;

  for (int tile = 0; tile < C / TILE; ++tile) {
    const int ibase = tile * TILE;
#pragma unroll
    for (int j = 0; j < TILE; ++j) {
      const int i = ibase + j;
      const int tt = t0 + i;
      const float xt = xb[j & 7];           // TILE % 8 == 0 -> ring stays aligned
      int tp = i + 8;
      tp = (tp < C) ? tp : (C - 1);         // clamped re-load at tail (L1-hot)
      xb[j & 7] = sp[(t0 + tp) * F];
      float w;
      if (tt != 0) {          // wave-uniform (only chunk 0, first step sees tt==0)
        m = 0.5f * (m + xt);
        const float d = xt - m;
        v = 0.5f * fmaf(d, d, v);
        c = 0.5f * fmaf(d, xl - m, c);
        const float ac = c * rsqrtf(fmaf(v, v, EPSC));
        w = 1.0f - fabsf(ac);
      } else {
        w = 1.0f;             // t=0: ac=0 -> irrelevance=1; state stays initial
      }
      xl = xt;
      lt[wv][j][lane] = w;    // consecutive lanes -> consecutive addrs, conflict-free
    }
    __syncthreads();
    // transpose-reduce: lane l sums lt[wv][l&31][(l>>5)*32 .. +31]
    // bank = (tr*65 + half*32 + k) % 32 = (tr + k) % 32 -> 2 lanes/bank (free)
    float s = 0.f;
#pragma unroll
    for (int k = 0; k < 32; ++k) s += lt[wv][tr][half * 32 + k];
    s += __shfl_xor(s, 32, 64);
    if (half == 0) ws[WS_IRR + b * T + t0 + ibase + tr] = s;  // 128B coalesced
    __syncthreads();
  }

  // ---- MSE partial (input/target are (B,T,1) -> B*T floats each) ----
  float macc = 0.f;
  const int gid = blockIdx.x * blockDim.x + threadIdx.x;
  const int nt = gridDim.x * blockDim.x;
  const int R = B * T;
  for (int i = gid; i < R; i += nt) {
    const float d = inp[i] - tgt[i];
    macc = fmaf(d, d, macc);
  }
#pragma unroll
  for (int off = 32; off; off >>= 1) macc += __shfl_xor(macc, off, 64);
  __shared__ float sm[4];
  if (lane == 0) sm[wv] = macc;
  __syncthreads();
  if (threadIdx.x == 0)
    ws[WS_MSE + blockIdx.x] = (sm[0] + sm[1]) + (sm[2] + sm[3]);
}

// ---------------------------------------------------------------------------
// Kernel 2: penalty dot = sum over (b,t,h) of fg * wsum[b,t]. Pure streaming:
// 2048 blocks x 256 threads = 32 waves/CU, float4 fg loads (16B/lane), one
// broadcast wsum load per wave-iteration (i>>6 identical across the wave,
// L2-hot: wsum is 1 MB). 256 MB at HBM roofline.
// ---------------------------------------------------------------------------
__global__ __launch_bounds__(256) void k_dot(
    const float* __restrict__ fg,
    float* __restrict__ ws) {
  const float* __restrict__ irr = ws + WS_IRR;
  const float4* __restrict__ fg4 = reinterpret_cast<const float4*>(fg);
  constexpr int N4 = B * T * (H / 4);        // 16,777,216 float4s
  constexpr int STRIDE = DOT_BLOCKS * 256;   // 524,288 -> exactly 32 iters/thread
  const int gid = blockIdx.x * 256 + threadIdx.x;
  float acc = 0.f;
#pragma unroll 4
  for (int i = gid; i < N4; i += STRIDE) {
    const float4 q = fg4[i];
    const float r = irr[i >> 6];             // H/4 = 64 float4 per (b,t) row
    acc = fmaf((q.x + q.y) + (q.z + q.w), r, acc);
  }
#pragma unroll
  for (int off = 32; off; off >>= 1) acc += __shfl_xor(acc, off, 64);
  __shared__ float sm[4];
  if ((threadIdx.x & 63) == 0) sm[threadIdx.x >> 6] = acc;
  __syncthreads();
  if (threadIdx.x == 0)
    ws[WS_PEN + blockIdx.x] = (sm[0] + sm[1]) + (sm[2] + sm[3]);
}

// ---------------------------------------------------------------------------
// Final reduce: 2048 penalty partials + 512 mse partials (10 KB, L2-hot).
// ---------------------------------------------------------------------------
__global__ __launch_bounds__(256) void k_reduce(
    const float* __restrict__ ws,
    float* __restrict__ out) {
  float p = 0.f, mt = 0.f;
#pragma unroll
  for (int i = 0; i < DOT_BLOCKS / 256; ++i)
    p += ws[WS_PEN + threadIdx.x + i * 256];
#pragma unroll
  for (int i = 0; i < SCAN_BLOCKS / 256; ++i)
    mt += ws[WS_MSE + threadIdx.x + i * 256];
#pragma unroll
  for (int off = 32; off; off >>= 1) {
    p += __shfl_xor(p, off, 64);
    mt += __shfl_xor(mt, off, 64);
  }
  __shared__ float sm[8];
  if ((threadIdx.x & 63) == 0) {
    sm[(threadIdx.x >> 6) * 2] = p;
    sm[(threadIdx.x >> 6) * 2 + 1] = mt;
  }
  __syncthreads();
  if (threadIdx.x == 0) {
    const float pt = sm[0] + sm[2] + sm[4] + sm[6];
    const float ms = sm[1] + sm[3] + sm[5] + sm[7];
    const float R = (float)B * (float)T;
    const float pscale = ALPHAC / (R * (float)H * (float)F);
    out[0] = ms / R + pt * pscale;
  }
}

extern "C" void kernel_launch(void* const* d_in, const int* in_sizes, int n_in,
                              void* d_out, int out_size, void* d_ws, size_t ws_size,
                              hipStream_t stream) {
  const float* inp = (const float*)d_in[0];   // (B,T,1)
  const float* tgt = (const float*)d_in[1];   // (B,T,1)
  const float* seq = (const float*)d_in[2];   // (B,T,F)
  const float* fg  = (const float*)d_in[3];   // (B,T,H)
  float* out = (float*)d_out;                 // scalar
  float* ws  = (float*)d_ws;

  k_scan<<<SCAN_BLOCKS, 256, 0, stream>>>(seq, inp, tgt, ws);
  k_dot<<<DOT_BLOCKS, 256, 0, stream>>>(fg, ws);
  k_reduce<<<1, 256, 0, stream>>>(ws, out);
}

// Round 3
// 406.830 us; speedup vs baseline: 1.0129x; 1.0129x over previous
//
#include <hip/hip_runtime.h>

// Problem constants: B=64, T=4096, F=64, H=256, LAM=0.5, LAG=1, ALPHA=0.5, EPS=1e-8
constexpr int B = 64;
constexpr int T = 4096;
constexpr int F = 64;       // == wavefront size; lane <-> feature
constexpr int H = 256;
constexpr float EPSC = 1e-8f;
constexpr float ALPHAC = 0.5f;

constexpr int C = 128;              // scan chunk length (one wave-task per chunk)
constexpr int W = 48;               // warmup steps (lambda=0.5 -> 2^-48 state error)
constexpr int CHUNKS = T / C;       // 32 chunks per batch row
constexpr int NTASK = B * CHUNKS;   // 2048 wave-tasks
constexpr int K_BLOCKS = NTASK / 4; // 512 blocks x 4 waves
constexpr int TILE = 32;            // t-steps buffered per wave-local reduce

// ws layout (floats): [0, 2048) penalty partials (per wave), [2048, 2560) mse partials (per block)
#define WS_PEN 0
#define WS_MSE NTASK

// ---------------------------------------------------------------------------
// Single streaming pass: per wave-task (b, chunk) run the EWA scan over 128
// t-steps. Per step: float4 fg load (prefetch ring) -> per-lane partial sum
// g[j]; seq load -> scan update -> w = 1-|ac| -> one conflict-free LDS write.
// Every 32 steps (wave-LOCAL, no __syncthreads: per-wave LDS slice):
// transpose-reduce w across lanes via LDS (2 lanes/bank = free), store wsum
// half-sums, then acc += wsum[j]*g[j] with broadcast LDS reads. No shfl and
// no barrier anywhere in the main loop -> pure stream at 346 MB total.
// MSE folded in as a grid-stride tail.
// ---------------------------------------------------------------------------
__global__ __launch_bounds__(256) void k_fused(
    const float* __restrict__ seq,
    const float* __restrict__ fg,
    const float* __restrict__ inp,
    const float* __restrict__ tgt,
    float* __restrict__ ws) {
  __shared__ float lt[4][TILE][65];   // 33.3 KB; write bank = lane%32, read bank = (tr+k)%32
  __shared__ float ls[4][2][TILE];    // wsum half-sums per wave
  const int lane = threadIdx.x & 63;
  const int wv = threadIdx.x >> 6;
  const int task = blockIdx.x * 4 + wv;
  const int b = task / CHUNKS;
  const int ci = task % CHUNKS;
  const int t0 = ci * C;

  const float* sp = seq + (size_t)b * T * F + lane;        // + t*F
  const float* gp = fg + (size_t)b * T * H + lane * 4;     // + t*H (float4)

  float m = 0.f, v = 0.f, c = 0.f;
  float xl = 0.f;

  if (ci == 0) {
    v = EPSC;  // exact initial state; t=0 handled in-loop (w=1 contribution)
  } else {
    // warmup: 48 seq-only steps, pipelined depth 4 (fully unrolled, const trip)
    const int ts = t0 - W;
    xl = sp[(ts - 1) * F];
    float xw[4];
#pragma unroll
    for (int j = 0; j < 4; ++j) xw[j] = sp[(ts + j) * F];
#pragma unroll
    for (int i = 0; i < W; ++i) {
      const float xt = xw[i & 3];
      if (i + 4 < W) xw[i & 3] = sp[(ts + i + 4) * F];
      m = 0.5f * (m + xt);
      const float d = xt - m;
      v = 0.5f * fmaf(d, d, v);
      c = 0.5f * fmaf(d, xl - m, c);
      xl = xt;
    }
  }

  // main loop: C steps in C/TILE tiles; prefetch rings fg depth 4, seq depth 8
  float4 qb[4];
  float xb[8];
#pragma unroll
  for (int j = 0; j < 4; ++j)
    qb[j] = *reinterpret_cast<const float4*>(gp + (size_t)(t0 + j) * H);
#pragma unroll
  for (int j = 0; j < 8; ++j) xb[j] = sp[(t0 + j) * F];

  const int tr = lane & 31;
  const int half = lane >> 5;
  float g[TILE];                      // per-lane fg partial sums for the tile
  float acc = 0.f, acc2 = 0.f;

  for (int tile = 0; tile < C / TILE; ++tile) {
    const int ibase = tile * TILE;
#pragma unroll
    for (int j = 0; j < TILE; ++j) {
      const int i = ibase + j;
      const int tt = t0 + i;
      const float4 q = qb[i & 3];
      const float xt = xb[i & 7];
      int tq = i + 4;
      tq = (tq < C) ? tq : (C - 1);   // clamped re-load at tail (L1-hot)
      qb[i & 3] = *reinterpret_cast<const float4*>(gp + (size_t)(t0 + tq) * H);
      int tp = i + 8;
      tp = (tp < C) ? tp : (C - 1);
      xb[i & 7] = sp[(t0 + tp) * F];

      g[j] = (q.x + q.y) + (q.z + q.w);

      float w;
      if (tt != 0) {          // wave-uniform (only chunk 0, first step sees tt==0)
        m = 0.5f * (m + xt);
        const float d = xt - m;
        v = 0.5f * fmaf(d, d, v);
        c = 0.5f * fmaf(d, xl - m, c);
        const float ac = c * rsqrtf(fmaf(v, v, EPSC));
        w = 1.0f - fabsf(ac);
      } else {
        w = 1.0f;             // t=0: ac=0 -> irrelevance=1; state stays initial
      }
      xl = xt;
      lt[wv][j][lane] = w;    // consecutive lanes -> consecutive banks, conflict-free
    }
    // wave-local transpose-reduce (same-wave LDS RAW: compiler inserts lgkmcnt)
    // read bank = (tr*65 + half*32 + k) % 32 = (tr + k) % 32 -> 2 lanes/bank (free)
    float s = 0.f;
#pragma unroll
    for (int k = 0; k < 32; ++k) s += lt[wv][tr][half * 32 + k];
    ls[wv][half][tr] = s;     // 64 consecutive floats, conflict-free
    // dot: wsum(j) = ls[0][j]+ls[1][j] (broadcast reads), times per-lane g[j]
#pragma unroll
    for (int j = 0; j < TILE; j += 2) {
      acc  = fmaf(ls[wv][0][j]     + ls[wv][1][j],     g[j],     acc);
      acc2 = fmaf(ls[wv][0][j + 1] + ls[wv][1][j + 1], g[j + 1], acc2);
    }
  }
  acc += acc2;

#pragma unroll
  for (int off = 32; off; off >>= 1) acc += __shfl_xor(acc, off, 64);
  if (lane == 0) ws[WS_PEN + task] = acc;

  // ---- MSE partial (input/target are (B,T,1) -> B*T floats each) ----
  float macc = 0.f;
  const int gid = blockIdx.x * blockDim.x + threadIdx.x;
  const int nt = gridDim.x * blockDim.x;
  const int R = B * T;
  for (int i = gid; i < R; i += nt) {
    const float d = inp[i] - tgt[i];
    macc = fmaf(d, d, macc);
  }
#pragma unroll
  for (int off = 32; off; off >>= 1) macc += __shfl_xor(macc, off, 64);
  __shared__ float sm[4];
  if (lane == 0) sm[wv] = macc;
  __syncthreads();
  if (threadIdx.x == 0)
    ws[WS_MSE + blockIdx.x] = (sm[0] + sm[1]) + (sm[2] + sm[3]);
}

// ---------------------------------------------------------------------------
// Final reduce: 2048 penalty partials + 512 mse partials (10 KB, L2-hot).
// ---------------------------------------------------------------------------
__global__ __launch_bounds__(256) void k_reduce(
    const float* __restrict__ ws,
    float* __restrict__ out) {
  float p = 0.f, mt = 0.f;
#pragma unroll
  for (int i = 0; i < NTASK / 256; ++i)
    p += ws[WS_PEN + threadIdx.x + i * 256];
#pragma unroll
  for (int i = 0; i < K_BLOCKS / 256; ++i)
    mt += ws[WS_MSE + threadIdx.x + i * 256];
#pragma unroll
  for (int off = 32; off; off >>= 1) {
    p += __shfl_xor(p, off, 64);
    mt += __shfl_xor(mt, off, 64);
  }
  __shared__ float sm[8];
  if ((threadIdx.x & 63) == 0) {
    sm[(threadIdx.x >> 6) * 2] = p;
    sm[(threadIdx.x >> 6) * 2 + 1] = mt;
  }
  __syncthreads();
  if (threadIdx.x == 0) {
    const float pt = sm[0] + sm[2] + sm[4] + sm[6];
    const float ms = sm[1] + sm[3] + sm[5] + sm[7];
    const float R = (float)B * (float)T;
    const float pscale = ALPHAC / (R * (float)H * (float)F);
    out[0] = ms / R + pt * pscale;
  }
}

extern "C" void kernel_launch(void* const* d_in, const int* in_sizes, int n_in,
                              void* d_out, int out_size, void* d_ws, size_t ws_size,
                              hipStream_t stream) {
  const float* inp = (const float*)d_in[0];   // (B,T,1)
  const float* tgt = (const float*)d_in[1];   // (B,T,1)
  const float* seq = (const float*)d_in[2];   // (B,T,F)
  const float* fg  = (const float*)d_in[3];   // (B,T,H)
  float* out = (float*)d_out;                 // scalar
  float* ws  = (float*)d_ws;

  k_fused<<<K_BLOCKS, 256, 0, stream>>>(seq, fg, inp, tgt, ws);
  k_reduce<<<1, 256, 0, stream>>>(ws, out);
}